// Round 5
// baseline (1459.980 us; speedup 1.0000x reference)
//
#include <hip/hip_runtime.h>

// mLSTM block forward, MI355X gfx950.
// Round 5: half-K-phase GEMM engine with 4-deep LDS ring + counted vmcnt(8)
// (T3+T4), single barrier/phase, swizzled LDS (2-way, free), setprio (T5),
// XCD swizzle (T1). Applied to gemm256/ifgate256/denom. qkv stay 128^2.

typedef __bf16 bf16_t;
typedef bf16_t bf16x8 __attribute__((ext_vector_type(8)));
typedef bf16_t bf16x4 __attribute__((ext_vector_type(4)));
typedef float f32x4 __attribute__((ext_vector_type(4)));

#define B_ROWS 8192
#define DMODEL 1024
#define HDIM   2048

__device__ __forceinline__ void gload_lds16(const void* g, void* s) {
  __builtin_amdgcn_global_load_lds(
      (const __attribute__((address_space(1))) void*)g,
      (__attribute__((address_space(3))) void*)s, 16, 0, 0);
}

__device__ __forceinline__ float sigmoidf_(float x) { return 1.f / (1.f + __expf(-x)); }
__device__ __forceinline__ float siluf_(float x)    { return x / (1.f + __expf(-x)); }

// Bijective XCD swizzle of a linear block id (T1, m204 variant).
__device__ __forceinline__ int xcd_swz(int lin, int nwg) {
  const int q = nwg >> 3, r = nwg & 7;
  const int xcd = lin & 7, sub = lin >> 3;
  return (xcd < r ? xcd * (q + 1) : r * (q + 1) + (xcd - r) * q) + sub;
}

// ---------------------------------------------------------------------------
// Transpose + convert: in f32 (R x C) -> out bf16 (C x R). Batched over z.
__global__ __launch_bounds__(256) void wtrans_kernel(
    const float* __restrict__ in, bf16_t* __restrict__ out, int R, int C) {
  const int z = blockIdx.z;
  in  += (size_t)z * R * C;
  out += (size_t)z * R * C;
  __shared__ float tile[64][65];
  const int t = threadIdx.x;
  const int r0 = blockIdx.y * 64, c0 = blockIdx.x * 64;
#pragma unroll
  for (int j = 0; j < 4; ++j) {
    const int r = j * 16 + (t >> 4);
    const int c = (t & 15) * 4;
    float4 v = *(const float4*)&in[(size_t)(r0 + r) * C + c0 + c];
    tile[r][c] = v.x; tile[r][c + 1] = v.y; tile[r][c + 2] = v.z; tile[r][c + 3] = v.w;
  }
  __syncthreads();
#pragma unroll
  for (int j = 0; j < 2; ++j) {
    const int wi = j * 256 + t;
    const int oc = wi >> 3;
    const int orr = (wi & 7) * 8;
    bf16x8 v;
#pragma unroll
    for (int u = 0; u < 8; ++u) v[u] = (bf16_t)tile[orr + u][oc];
    *(bf16x8*)&out[(size_t)(c0 + oc) * R + r0 + orr] = v;
  }
}

// ---------------------------------------------------------------------------
// LayerNorm over D=1024, f32 in -> bf16 out. One block (256 thr) per row.
__global__ __launch_bounds__(256) void ln_kernel(
    const float* __restrict__ x, const float* __restrict__ g,
    const float* __restrict__ b, bf16_t* __restrict__ out) {
  const int row = blockIdx.x;
  const int t = threadIdx.x;
  const float* xr = x + (size_t)row * DMODEL;
  float4 v = *(const float4*)&xr[t * 4];
  float s = v.x + v.y + v.z + v.w;
  float s2 = v.x * v.x + v.y * v.y + v.z * v.z + v.w * v.w;
#pragma unroll
  for (int off = 1; off < 64; off <<= 1) {
    s += __shfl_xor(s, off, 64);
    s2 += __shfl_xor(s2, off, 64);
  }
  __shared__ float ps[8];
  const int w = t >> 6;
  if ((t & 63) == 0) { ps[w] = s; ps[4 + w] = s2; }
  __syncthreads();
  s = ps[0] + ps[1] + ps[2] + ps[3];
  s2 = ps[4] + ps[5] + ps[6] + ps[7];
  const float mu = s / (float)DMODEL;
  const float var = s2 / (float)DMODEL - mu * mu;
  const float rstd = rsqrtf(var + 1e-5f);
  float4 gg = *(const float4*)&g[t * 4];
  float4 bb = *(const float4*)&b[t * 4];
  bf16x4 o;
  o[0] = (bf16_t)((v.x - mu) * rstd * gg.x + bb.x);
  o[1] = (bf16_t)((v.y - mu) * rstd * gg.y + bb.y);
  o[2] = (bf16_t)((v.z - mu) * rstd * gg.z + bb.z);
  o[3] = (bf16_t)((v.w - mu) * rstd * gg.w + bb.w);
  *(bf16x4*)&out[(size_t)row * DMODEL + t * 4] = o;
}

// ---------------------------------------------------------------------------
// Causal conv1d (k=4, left pad 3) + SiLU. bf16 in -> bf16 out.
__global__ __launch_bounds__(256) void conv_kernel(
    const bf16_t* __restrict__ xin, const float* __restrict__ cw,
    const float* __restrict__ cb, bf16_t* __restrict__ yb) {
  const size_t idx = (size_t)blockIdx.x * blockDim.x + threadIdx.x;
  const int row = (int)(idx >> 9);
  const int c0 = ((int)idx & 511) * 4;
  const bf16_t* xr = xin + (size_t)row * HDIM;
  const float w0 = cw[0], w1 = cw[1], w2 = cw[2], w3 = cw[3], bb = cb[0];
  float xm3 = 0.f, xm2 = 0.f, xm1 = 0.f;
  if (c0 > 0) {
    bf16x4 p = *(const bf16x4*)&xr[c0 - 4];
    xm3 = (float)p[1]; xm2 = (float)p[2]; xm1 = (float)p[3];
  }
  bf16x4 xv4 = *(const bf16x4*)&xr[c0];
  float x0 = (float)xv4[0], x1 = (float)xv4[1], x2 = (float)xv4[2], x3 = (float)xv4[3];
  float y0 = w0 * xm3 + w1 * xm2 + w2 * xm1 + w3 * x0 + bb;
  float y1 = w0 * xm2 + w1 * xm1 + w2 * x0 + w3 * x1 + bb;
  float y2 = w0 * xm1 + w1 * x0 + w2 * x1 + w3 * x2 + bb;
  float y3 = w0 * x0 + w1 * x1 + w2 * x2 + w3 * x3 + bb;
  bf16x4 yb4;
  yb4[0] = (bf16_t)siluf_(y0); yb4[1] = (bf16_t)siluf_(y1);
  yb4[2] = (bf16_t)siluf_(y2); yb4[3] = (bf16_t)siluf_(y3);
  *(bf16x4*)&yb[(size_t)row * HDIM + c0] = yb4;
}

// ---------------------------------------------------------------------------
// h_t + GroupNorm(8 groups of 256) + skip + silu-gate. One block per row.
__global__ __launch_bounds__(256) void hgn_kernel(
    const bf16_t* __restrict__ o_pre, const float* __restrict__ q,
    const float* __restrict__ c_t, const float* __restrict__ denomf,
    const bf16_t* __restrict__ skip, const bf16_t* __restrict__ upr,
    const float* __restrict__ gn_g, const float* __restrict__ gn_b,
    float* __restrict__ h_out, bf16_t* __restrict__ act_out) {
  const int row = blockIdx.x;
  const int t = threadIdx.x;
  const size_t base = (size_t)row * HDIM + t * 8;
  const int i0 = t * 8;
  bf16x8 o8 = *(const bf16x8*)&o_pre[base];
  float h[8];
  float s = 0.f, s2 = 0.f;
#pragma unroll
  for (int j = 0; j < 2; ++j) {
    float4 qv = *(const float4*)&q[base + j * 4];
    float4 cv = *(const float4*)&c_t[base + j * 4];
#pragma unroll
    for (int u = 0; u < 4; ++u) {
      const int k = j * 4 + u;
      float hv = sigmoidf_((float)o8[k]) * ((const float*)&cv)[u] *
                 ((const float*)&qv)[u] / denomf[i0 + k];
      h[k] = hv;
      s += hv;
      s2 += hv * hv;
    }
  }
#pragma unroll
  for (int off = 1; off < 32; off <<= 1) {
    s += __shfl_xor(s, off, 64);
    s2 += __shfl_xor(s2, off, 64);
  }
  const float mu = s / 256.f;
  const float var = s2 / 256.f - mu * mu;
  const float rstd = rsqrtf(var + 1e-5f);
  float4 h0 = {h[0], h[1], h[2], h[3]};
  float4 h1 = {h[4], h[5], h[6], h[7]};
  *(float4*)&h_out[base] = h0;
  *(float4*)&h_out[base + 4] = h1;
  bf16x8 sk8 = *(const bf16x8*)&skip[base];
  bf16x8 up8 = *(const bf16x8*)&upr[base];
  bf16x8 a8;
#pragma unroll
  for (int j = 0; j < 2; ++j) {
    float4 gv = *(const float4*)&gn_g[i0 + j * 4];
    float4 bv = *(const float4*)&gn_b[i0 + j * 4];
#pragma unroll
    for (int u = 0; u < 4; ++u) {
      const int k = j * 4 + u;
      float y = (h[k] - mu) * rstd * ((const float*)&gv)[u] + ((const float*)&bv)[u];
      y = (y + (float)sk8[k]) * siluf_((float)up8[k]);
      a8[k] = (bf16_t)y;
    }
  }
  *(bf16x8*)&act_out[base] = a8;
}

// ---------------------------------------------------------------------------
// 128^2 / BK=32 GEMM (kept for small block-diagonal qkv).
template <int OUTMODE, bool RES>
__global__ __launch_bounds__(256) void gemm_kernel(
    const bf16_t* __restrict__ A, int lda, const bf16_t* __restrict__ Bt, int ldb,
    const float* __restrict__ bias, float* __restrict__ C, bf16_t* __restrict__ Cb,
    int ldc, const float* __restrict__ res, int ldres, int K, float scale,
    int zA, long long zB, int zBias, int zC) {
  const int z = blockIdx.z;
  A += (size_t)z * zA;
  Bt += (size_t)z * zB;
  if (bias) bias += (size_t)z * zBias;
  if (OUTMODE == 0) C += (size_t)z * zC; else Cb += (size_t)z * zC;
  const int brow = blockIdx.y * 128;
  const int bcol = blockIdx.x * 128;
  __shared__ bf16_t As[128 * 32];
  __shared__ bf16_t Bs[128 * 32];
  const int tid = threadIdx.x;
  const int w = tid >> 6, l = tid & 63;
  const int wr = w >> 1, wc = w & 1;
  const int lr = l & 15, kg = l >> 4;
  const int l4 = l & 3, ld4 = l >> 2;

  f32x4 acc[4][4];
  const f32x4 fzero = {0.f, 0.f, 0.f, 0.f};
#pragma unroll
  for (int m = 0; m < 4; ++m)
#pragma unroll
    for (int n = 0; n < 4; ++n) acc[m][n] = fzero;

  for (int kt = 0; kt < K; kt += 32) {
#pragma unroll
    for (int j = 0; j < 2; ++j) {
      const int rowX = w * 32 + j * 16 + ld4;
      gload_lds16(A + (size_t)(brow + rowX) * lda + kt + l4 * 8, &As[w * 1024 + j * 512]);
      gload_lds16(Bt + (size_t)(bcol + rowX) * ldb + kt + l4 * 8, &Bs[w * 1024 + j * 512]);
    }
    __syncthreads();
    bf16x8 a[4], b[4];
#pragma unroll
    for (int m = 0; m < 4; ++m)
      a[m] = *(const bf16x8*)&As[(wr * 64 + m * 16 + lr) * 32 + kg * 8];
#pragma unroll
    for (int n = 0; n < 4; ++n)
      b[n] = *(const bf16x8*)&Bs[(wc * 64 + n * 16 + lr) * 32 + kg * 8];
#pragma unroll
    for (int m = 0; m < 4; ++m)
#pragma unroll
      for (int n = 0; n < 4; ++n)
        acc[m][n] = __builtin_amdgcn_mfma_f32_16x16x32_bf16(a[m], b[n], acc[m][n], 0, 0, 0);
    __syncthreads();
  }

#pragma unroll
  for (int m = 0; m < 4; ++m) {
    const int row0 = brow + wr * 64 + m * 16 + kg * 4;
#pragma unroll
    for (int n = 0; n < 4; ++n) {
      const int col = bcol + wc * 64 + n * 16 + lr;
      const float bv = bias ? bias[col] : 0.f;
#pragma unroll
      for (int r = 0; r < 4; ++r) {
        const int row = row0 + r;
        float v = (acc[m][n][r] + bv) * scale;
        if (RES) v += res[(size_t)row * ldres + col];
        if (OUTMODE == 0) C[(size_t)row * ldc + col] = v;
        else Cb[(size_t)row * ldc + col] = (bf16_t)v;
      }
    }
  }
}

// ---------------------------------------------------------------------------
// 256^2 GEMM, half-K (32) phases, 4-deep LDS ring, counted vmcnt(8).
// Per phase: vmcnt -> barrier -> stage(h+3) -> ds_read 12 -> lgkm -> 32 MFMA.
// LDS slot layout: [row][4 x 16B], 16B-slot s' = kg ^ ((row>>1)&3) (2-way, free).
// Staging inverts the swizzle on the global source (linear gload_lds dest).
template <int OUTMODE /*0=f32,2=bf16*/, bool RES>
__global__ __launch_bounds__(512, 2) void gemm256_kernel(
    const bf16_t* __restrict__ A, int lda, const bf16_t* __restrict__ Bt, int ldb,
    const float* __restrict__ bias, float* __restrict__ C, bf16_t* __restrict__ Cb,
    int ldc, const float* __restrict__ res, int ldres, int K, float scale,
    long long zA, long long zB, long long zC) {
  const int z = blockIdx.z;
  A += (size_t)z * zA;
  Bt += (size_t)z * zB;
  if (OUTMODE == 0) C += (size_t)z * zC; else Cb += (size_t)z * zC;

  const int nwg = gridDim.x * gridDim.y;
  const int lin2 = xcd_swz(blockIdx.y * gridDim.x + blockIdx.x, nwg);
  const int bx = lin2 % gridDim.x, by = lin2 / gridDim.x;
  const int brow = by * 256, bcol = bx * 256;

  __shared__ bf16_t As[4][256 * 32];
  __shared__ bf16_t Bs[4][256 * 32];

  const int tid = threadIdx.x;
  const int l = tid & 63;
  const int w = tid >> 6;
  const int wr = w >> 2, wn = w & 3;  // 2 (M) x 4 (N) waves
  const int lr = l & 15, kg = l >> 4;

  f32x4 acc[8][4];
  const f32x4 fzero = {0.f, 0.f, 0.f, 0.f};
#pragma unroll
  for (int m = 0; m < 8; ++m)
#pragma unroll
    for (int n = 0; n < 4; ++n) acc[m][n] = fzero;

  const int NT2 = K >> 5;  // half-K phases
  const bf16_t* Ag = A + (size_t)brow * lda;
  const bf16_t* Bg = Bt + (size_t)bcol * ldb;

  auto stage = [&](int hh) {
    const int slot = hh & 3;
    const int kb = hh * 32;
#pragma unroll
    for (int j = 0; j < 2; ++j) {
      const int L = j * 512 + tid;
      const int row = L >> 2;
      const int s = (L & 3) ^ ((L >> 3) & 3);  // inverse swizzle on source
      gload_lds16(Ag + (size_t)row * lda + kb + s * 8, (char*)&As[slot][0] + L * 16);
      gload_lds16(Bg + (size_t)row * ldb + kb + s * 8, (char*)&Bs[slot][0] + L * 16);
    }
  };

  stage(0); stage(1); stage(2);

  for (int h = 0; h < NT2; ++h) {
    if (h >= NT2 - 1)      asm volatile("s_waitcnt vmcnt(0)" ::: "memory");
    else if (h == NT2 - 2) asm volatile("s_waitcnt vmcnt(4)" ::: "memory");
    else                   asm volatile("s_waitcnt vmcnt(8)" ::: "memory");
    __builtin_amdgcn_s_barrier();
    __builtin_amdgcn_sched_barrier(0);
    if (h + 3 < NT2) stage(h + 3);
    const int buf = h & 3;
    bf16x8 a[8], b[4];
#pragma unroll
    for (int n = 0; n < 4; ++n) {
      const int r = wn * 64 + n * 16 + lr;
      b[n] = *(const bf16x8*)&Bs[buf][r * 32 + ((kg ^ ((r >> 1) & 3)) * 8)];
    }
#pragma unroll
    for (int m = 0; m < 8; ++m) {
      const int r = wr * 128 + m * 16 + lr;
      a[m] = *(const bf16x8*)&As[buf][r * 32 + ((kg ^ ((r >> 1) & 3)) * 8)];
    }
    asm volatile("s_waitcnt lgkmcnt(0)" ::: "memory");
    __builtin_amdgcn_sched_barrier(0);
    __builtin_amdgcn_s_setprio(1);
#pragma unroll
    for (int m = 0; m < 8; ++m)
#pragma unroll
      for (int n = 0; n < 4; ++n)
        acc[m][n] = __builtin_amdgcn_mfma_f32_16x16x32_bf16(a[m], b[n], acc[m][n], 0, 0, 0);
    __builtin_amdgcn_s_setprio(0);
  }

#pragma unroll
  for (int m = 0; m < 8; ++m) {
    const int row0 = brow + wr * 128 + m * 16 + kg * 4;
#pragma unroll
    for (int n = 0; n < 4; ++n) {
      const int col = bcol + wn * 64 + n * 16 + lr;
      const float bvv = bias ? bias[col] : 0.f;
#pragma unroll
      for (int r = 0; r < 4; ++r) {
        const int row = row0 + r;
        float v = (acc[m][n][r] + bvv) * scale;
        if (RES) v += res[(size_t)row * ldres + col];
        if (OUTMODE == 0) C[(size_t)row * ldc + col] = v;
        else Cb[(size_t)row * ldc + col] = (bf16_t)v;
      }
    }
  }
}

// ---------------------------------------------------------------------------
// 256x128 dual-B GEMM + fused mLSTM gate, same half-K ring engine.
// Loads/thread/phase: 2 A + 1 Bi + 1 Bf = 4 => same vmcnt constants.
__global__ __launch_bounds__(512, 2) void ifgate256_kernel(
    const bf16_t* __restrict__ A,                                  // xconv [B][H]
    const bf16_t* __restrict__ Bi, const bf16_t* __restrict__ Bf,  // [H][H] k-major
    const float* __restrict__ bi, const float* __restrict__ bfv,
    const float* __restrict__ m_prev, const float* __restrict__ c_prev,
    const float* __restrict__ n_prev,
    const bf16_t* __restrict__ vb, const bf16_t* __restrict__ kb,
    float* __restrict__ m_out, float* __restrict__ c_out, float* __restrict__ n_out) {
  const int nwg = gridDim.x * gridDim.y;
  const int lin2 = xcd_swz(blockIdx.y * gridDim.x + blockIdx.x, nwg);
  const int bx = lin2 % gridDim.x, by = lin2 / gridDim.x;
  const int brow = by * 256, bcol = bx * 128;

  __shared__ bf16_t As[4][256 * 32];
  __shared__ bf16_t Bis[4][128 * 32];
  __shared__ bf16_t Bfs[4][128 * 32];

  const int tid = threadIdx.x;
  const int l = tid & 63;
  const int w = tid >> 6;
  const int wr = w >> 2, wn = w & 3;  // 2 (M) x 4 (N/32) waves
  const int lr = l & 15, kg = l >> 4;

  f32x4 acci[8][2], accf[8][2];
  const f32x4 fzero = {0.f, 0.f, 0.f, 0.f};
#pragma unroll
  for (int m = 0; m < 8; ++m)
#pragma unroll
    for (int n = 0; n < 2; ++n) { acci[m][n] = fzero; accf[m][n] = fzero; }

  const int NT2 = HDIM >> 5;
  const bf16_t* Ag = A + (size_t)brow * HDIM;
  const bf16_t* Big = Bi + (size_t)bcol * HDIM;
  const bf16_t* Bfg = Bf + (size_t)bcol * HDIM;

  auto stage = [&](int hh) {
    const int slot = hh & 3;
    const int kb2 = hh * 32;
#pragma unroll
    for (int j = 0; j < 2; ++j) {
      const int L = j * 512 + tid;
      const int row = L >> 2;
      const int s = (L & 3) ^ ((L >> 3) & 3);
      gload_lds16(Ag + (size_t)row * HDIM + kb2 + s * 8, (char*)&As[slot][0] + L * 16);
    }
    {
      const int L = tid;
      const int row = L >> 2;
      const int s = (L & 3) ^ ((L >> 3) & 3);
      gload_lds16(Big + (size_t)row * HDIM + kb2 + s * 8, (char*)&Bis[slot][0] + L * 16);
      gload_lds16(Bfg + (size_t)row * HDIM + kb2 + s * 8, (char*)&Bfs[slot][0] + L * 16);
    }
  };

  stage(0); stage(1); stage(2);

  for (int h = 0; h < NT2; ++h) {
    if (h >= NT2 - 1)      asm volatile("s_waitcnt vmcnt(0)" ::: "memory");
    else if (h == NT2 - 2) asm volatile("s_waitcnt vmcnt(4)" ::: "memory");
    else                   asm volatile("s_waitcnt vmcnt(8)" ::: "memory");
    __builtin_amdgcn_s_barrier();
    __builtin_amdgcn_sched_barrier(0);
    if (h + 3 < NT2) stage(h + 3);
    const int buf = h & 3;
    bf16x8 a[8], b1[2], b2[2];
#pragma unroll
    for (int n = 0; n < 2; ++n) {
      const int r = wn * 32 + n * 16 + lr;
      const int eo = r * 32 + ((kg ^ ((r >> 1) & 3)) * 8);
      b1[n] = *(const bf16x8*)&Bis[buf][eo];
      b2[n] = *(const bf16x8*)&Bfs[buf][eo];
    }
#pragma unroll
    for (int m = 0; m < 8; ++m) {
      const int r = wr * 128 + m * 16 + lr;
      a[m] = *(const bf16x8*)&As[buf][r * 32 + ((kg ^ ((r >> 1) & 3)) * 8)];
    }
    asm volatile("s_waitcnt lgkmcnt(0)" ::: "memory");
    __builtin_amdgcn_sched_barrier(0);
    __builtin_amdgcn_s_setprio(1);
#pragma unroll
    for (int m = 0; m < 8; ++m)
#pragma unroll
      for (int n = 0; n < 2; ++n) {
        acci[m][n] = __builtin_amdgcn_mfma_f32_16x16x32_bf16(a[m], b1[n], acci[m][n], 0, 0, 0);
        accf[m][n] = __builtin_amdgcn_mfma_f32_16x16x32_bf16(a[m], b2[n], accf[m][n], 0, 0, 0);
      }
    __builtin_amdgcn_s_setprio(0);
  }

#pragma unroll
  for (int m = 0; m < 8; ++m) {
    const int row0 = brow + wr * 128 + m * 16 + kg * 4;
#pragma unroll
    for (int n = 0; n < 2; ++n) {
      const int col = bcol + wn * 32 + n * 16 + lr;
      const float biv = bi[col], bfvv = bfv[col];
#pragma unroll
      for (int r = 0; r < 4; ++r) {
        const int row = row0 + r;
        const size_t idx = (size_t)row * HDIM + col;
        const float it = acci[m][n][r] + biv;
        const float ft = accf[m][n][r] + bfvv;
        const float m1 = m_prev[idx];
        const float mt = fmaxf(ft + m1, it);
        const float ig = __expf(it - mt);
        const float fg = __expf(ft + m1 - mt);
        const float v1 = (float)vb[idx], k1 = (float)kb[idx];
        m_out[idx] = mt;
        c_out[idx] = fg * c_prev[idx] + ig * (v1 * k1);
        n_out[idx] = fg * n_prev[idx] + ig * k1;
      }
    }
  }
}

// ---------------------------------------------------------------------------
// denom reduce: dmax[i] = max_j |sum_z part[z][i][j]| (4 split-K parts)
__global__ __launch_bounds__(256) void denom_reduce_kernel(
    const float* __restrict__ part, float* __restrict__ dmaxf) {
  const int i = blockIdx.x;
  const int t = threadIdx.x;
  float vmax = 0.f;
#pragma unroll
  for (int u = 0; u < 8; ++u) {
    const int j = u * 256 + t;
    float s = 0.f;
#pragma unroll
    for (int zz = 0; zz < 4; ++zz)
      s += part[(size_t)zz * HDIM * HDIM + (size_t)i * HDIM + j];
    vmax = fmaxf(vmax, fabsf(s));
  }
#pragma unroll
  for (int off = 1; off < 64; off <<= 1) vmax = fmaxf(vmax, __shfl_xor(vmax, off, 64));
  __shared__ float ps[4];
  if ((t & 63) == 0) ps[t >> 6] = vmax;
  __syncthreads();
  if (t == 0) dmaxf[i] = fmaxf(fmaxf(ps[0], ps[1]), fmaxf(ps[2], ps[3]));
}

// ---------------------------------------------------------------------------
extern "C" void kernel_launch(void* const* d_in, const int* in_sizes, int n_in,
                              void* d_out, int out_size, void* d_ws, size_t ws_size,
                              hipStream_t stream) {
  (void)in_sizes; (void)n_in; (void)out_size; (void)ws_size;
  const float* x      = (const float*)d_in[0];
  const float* ln_g   = (const float*)d_in[1];
  const float* ln_b   = (const float*)d_in[2];
  const float* Wupl   = (const float*)d_in[3];
  const float* bupl   = (const float*)d_in[4];
  const float* Wupr   = (const float*)d_in[5];
  const float* bupr   = (const float*)d_in[6];
  const float* conv_w = (const float*)d_in[7];
  const float* conv_b = (const float*)d_in[8];
  const float* Wskip  = (const float*)d_in[9];
  const float* bskip  = (const float*)d_in[10];
  const float* Wq     = (const float*)d_in[11];
  const float* bq     = (const float*)d_in[12];
  const float* Wk     = (const float*)d_in[13];
  const float* bk     = (const float*)d_in[14];
  const float* Wv     = (const float*)d_in[15];
  const float* bv     = (const float*)d_in[16];
  const float* Wi     = (const float*)d_in[17];
  const float* bi     = (const float*)d_in[18];
  const float* Wf     = (const float*)d_in[19];
  const float* bf_    = (const float*)d_in[20];
  const float* Wo     = (const float*)d_in[21];
  const float* bo     = (const float*)d_in[22];
  const float* gn_g   = (const float*)d_in[23];
  const float* gn_b   = (const float*)d_in[24];
  const float* Wdown  = (const float*)d_in[25];
  const float* bdown  = (const float*)d_in[26];
  const float* c_prev = (const float*)d_in[27];
  const float* n_prev = (const float*)d_in[28];
  const float* m_prev = (const float*)d_in[29];

  float* out_final = (float*)d_out;
  float* out_h = out_final + (size_t)B_ROWS * DMODEL;
  float* out_c = out_h + (size_t)B_ROWS * HDIM;
  float* out_n = out_c + (size_t)B_ROWS * HDIM;
  float* out_m = out_n + (size_t)B_ROWS * HDIM;

  char* ws = (char*)d_ws;
  size_t off = 0;
  auto alloc = [&](size_t bytes) -> void* {
    off = (off + 255) & ~(size_t)255;
    void* p = ws + off;
    off += bytes;
    return p;
  };
  const size_t BH = (size_t)B_ROWS * HDIM;
  const size_t BD = (size_t)B_ROWS * DMODEL;

  bf16_t* WuplT = (bf16_t*)alloc((size_t)DMODEL * HDIM * 2);
  bf16_t* WuprT = (bf16_t*)alloc((size_t)DMODEL * HDIM * 2);
  bf16_t* WskipT = (bf16_t*)alloc((size_t)HDIM * HDIM * 2);
  bf16_t* WiT = (bf16_t*)alloc((size_t)HDIM * HDIM * 2);
  bf16_t* WfT = (bf16_t*)alloc((size_t)HDIM * HDIM * 2);
  bf16_t* WoT = (bf16_t*)alloc((size_t)HDIM * HDIM * 2);
  bf16_t* WdownT = (bf16_t*)alloc((size_t)HDIM * DMODEL * 2);
  bf16_t* WqT = (bf16_t*)alloc((size_t)8 * 256 * 256 * 2);
  bf16_t* WkT = (bf16_t*)alloc((size_t)8 * 256 * 256 * 2);
  bf16_t* WvT = (bf16_t*)alloc((size_t)8 * 256 * 256 * 2);
  bf16_t* xnorm_b = (bf16_t*)alloc(BD * 2);
  bf16_t* xupl_b = (bf16_t*)alloc(BH * 2);
  bf16_t* xupr_b = (bf16_t*)alloc(BH * 2);
  bf16_t* xconv_b = (bf16_t*)alloc(BH * 2);
  bf16_t* xskip_b = (bf16_t*)alloc(BH * 2);
  bf16_t* o_b = (bf16_t*)alloc(BH * 2);
  float*  q_f = (float*)alloc(BH * 4);
  bf16_t* k_b = (bf16_t*)alloc(BH * 2);
  bf16_t* v_b = (bf16_t*)alloc(BH * 2);
  bf16_t* qT_b = (bf16_t*)alloc(BH * 2);
  bf16_t* nT_b = (bf16_t*)alloc(BH * 2);
  bf16_t* act_b = (bf16_t*)alloc(BH * 2);
  float*  part = (float*)alloc((size_t)4 * HDIM * HDIM * 4);
  float*  dmaxf = (float*)alloc(HDIM * 4);

  // ---- weights: transpose + convert to bf16 (N x K layout)
  wtrans_kernel<<<dim3(HDIM / 64, DMODEL / 64, 1), 256, 0, stream>>>(Wupl, WuplT, DMODEL, HDIM);
  wtrans_kernel<<<dim3(HDIM / 64, DMODEL / 64, 1), 256, 0, stream>>>(Wupr, WuprT, DMODEL, HDIM);
  wtrans_kernel<<<dim3(HDIM / 64, HDIM / 64, 1), 256, 0, stream>>>(Wskip, WskipT, HDIM, HDIM);
  wtrans_kernel<<<dim3(HDIM / 64, HDIM / 64, 1), 256, 0, stream>>>(Wi, WiT, HDIM, HDIM);
  wtrans_kernel<<<dim3(HDIM / 64, HDIM / 64, 1), 256, 0, stream>>>(Wf, WfT, HDIM, HDIM);
  wtrans_kernel<<<dim3(HDIM / 64, HDIM / 64, 1), 256, 0, stream>>>(Wo, WoT, HDIM, HDIM);
  wtrans_kernel<<<dim3(DMODEL / 64, HDIM / 64, 1), 256, 0, stream>>>(Wdown, WdownT, HDIM, DMODEL);
  wtrans_kernel<<<dim3(4, 4, 8), 256, 0, stream>>>(Wq, WqT, 256, 256);
  wtrans_kernel<<<dim3(4, 4, 8), 256, 0, stream>>>(Wk, WkT, 256, 256);
  wtrans_kernel<<<dim3(4, 4, 8), 256, 0, stream>>>(Wv, WvT, 256, 256);

  // ---- layernorm
  ln_kernel<<<B_ROWS, 256, 0, stream>>>(x, ln_g, ln_b, xnorm_b);

  // ---- up projections (bf16 outputs)
  gemm256_kernel<2, false><<<dim3(HDIM / 256, B_ROWS / 256, 1), 512, 0, stream>>>(
      xnorm_b, DMODEL, WuplT, DMODEL, bupl, nullptr, xupl_b, HDIM, nullptr, 0,
      DMODEL, 1.f, 0, 0, 0);
  gemm256_kernel<2, false><<<dim3(HDIM / 256, B_ROWS / 256, 1), 512, 0, stream>>>(
      xnorm_b, DMODEL, WuprT, DMODEL, bupr, nullptr, xupr_b, HDIM, nullptr, 0,
      DMODEL, 1.f, 0, 0, 0);

  // ---- causal conv + silu
  conv_kernel<<<(unsigned)(BH / 4 / 256), 256, 0, stream>>>(xupl_b, conv_w, conv_b, xconv_b);

  // ---- skip and o projections (bf16 out)
  gemm256_kernel<2, false><<<dim3(HDIM / 256, B_ROWS / 256, 1), 512, 0, stream>>>(
      xconv_b, HDIM, WskipT, HDIM, bskip, nullptr, xskip_b, HDIM, nullptr, 0,
      HDIM, 1.f, 0, 0, 0);
  gemm256_kernel<2, false><<<dim3(HDIM / 256, B_ROWS / 256, 1), 512, 0, stream>>>(
      xupl_b, HDIM, WoT, HDIM, bo, nullptr, o_b, HDIM, nullptr, 0,
      HDIM, 1.f, 0, 0, 0);

  // ---- block-diagonal q (f32), k (bf16, /16), v (bf16) — small K, old kernel
  gemm_kernel<0, false><<<dim3(2, B_ROWS / 128, 8), 256, 0, stream>>>(
      xconv_b, HDIM, WqT, 256, bq, q_f, nullptr, HDIM, nullptr, 0,
      256, 1.f, 256, 256 * 256, 256, 256);
  gemm_kernel<2, false><<<dim3(2, B_ROWS / 128, 8), 256, 0, stream>>>(
      xconv_b, HDIM, WkT, 256, bk, nullptr, k_b, HDIM, nullptr, 0,
      256, 0.0625f, 256, 256 * 256, 256, 256);
  gemm_kernel<2, false><<<dim3(2, B_ROWS / 128, 8), 256, 0, stream>>>(
      xupl_b, HDIM, WvT, 256, bv, nullptr, v_b, HDIM, nullptr, 0,
      256, 1.f, 256, 256 * 256, 256, 256);

  // ---- i/f dual GEMM + fused gate -> m_t, c_t, n_t
  ifgate256_kernel<<<dim3(HDIM / 128, B_ROWS / 256, 1), 512, 0, stream>>>(
      xconv_b, WiT, WfT, bi, bf_, m_prev, c_prev, n_prev, v_b, k_b,
      out_m, out_c, out_n);

  // ---- transpose q and n_t to k-major bf16 for the denom GEMM
  wtrans_kernel<<<dim3(HDIM / 64, B_ROWS / 64, 1), 256, 0, stream>>>(q_f, qT_b, B_ROWS, HDIM);
  wtrans_kernel<<<dim3(HDIM / 64, B_ROWS / 64, 1), 256, 0, stream>>>(out_n, nT_b, B_ROWS, HDIM);

  // ---- denom: split-K(4) GEMM partials + reduce
  gemm256_kernel<0, false><<<dim3(HDIM / 256, HDIM / 256, 4), 512, 0, stream>>>(
      nT_b, B_ROWS, qT_b, B_ROWS, nullptr, part, nullptr, HDIM, nullptr, 0,
      2048, 1.f, 2048, 2048, (long long)HDIM * HDIM);
  denom_reduce_kernel<<<HDIM, 256, 0, stream>>>(part, dmaxf);

  // ---- h_t + groupnorm + skip + silu gate
  hgn_kernel<<<B_ROWS, 256, 0, stream>>>(o_b, q_f, out_c, dmaxf, xskip_b,
                                         xupr_b, gn_g, gn_b, out_h, act_b);

  // ---- down projection + residual
  gemm256_kernel<0, true><<<dim3(DMODEL / 256, B_ROWS / 256, 1), 512, 0, stream>>>(
      act_b, HDIM, WdownT, HDIM, bdown, out_final, nullptr, DMODEL, x, DMODEL,
      HDIM, 1.f, 0, 0, 0);
}

// Round 6
// 1345.677 us; speedup vs baseline: 1.0849x; 1.0849x over previous
//
#include <hip/hip_runtime.h>

// mLSTM block forward, MI355X gfx950.
// Round 6: k-half-phase GEMM engine. Per BK=64 tile: 4 phases (kk,mh), LDS
// [2dbuf][2khalf][256][32]/operand, stage t+1 halves one-per-phase into dbuf^1,
// counted vmcnt(4) twice per tile (ledger-verified), 2 barriers/tile, no
// sched_barrier/asm-lgkm (compiler interleaves), setprio on MFMA clusters.

typedef __bf16 bf16_t;
typedef bf16_t bf16x8 __attribute__((ext_vector_type(8)));
typedef bf16_t bf16x4 __attribute__((ext_vector_type(4)));
typedef float f32x4 __attribute__((ext_vector_type(4)));

#define B_ROWS 8192
#define DMODEL 1024
#define HDIM   2048

__device__ __forceinline__ void gload_lds16(const void* g, void* s) {
  __builtin_amdgcn_global_load_lds(
      (const __attribute__((address_space(1))) void*)g,
      (__attribute__((address_space(3))) void*)s, 16, 0, 0);
}

__device__ __forceinline__ float sigmoidf_(float x) { return 1.f / (1.f + __expf(-x)); }
__device__ __forceinline__ float siluf_(float x)    { return x / (1.f + __expf(-x)); }

// Bijective XCD swizzle of a linear block id (T1, m204 variant).
__device__ __forceinline__ int xcd_swz(int lin, int nwg) {
  const int q = nwg >> 3, r = nwg & 7;
  const int xcd = lin & 7, sub = lin >> 3;
  return (xcd < r ? xcd * (q + 1) : r * (q + 1) + (xcd - r) * q) + sub;
}

// ---------------------------------------------------------------------------
// Transpose + convert: in f32 (R x C) -> out bf16 (C x R). Batched over z.
__global__ __launch_bounds__(256) void wtrans_kernel(
    const float* __restrict__ in, bf16_t* __restrict__ out, int R, int C) {
  const int z = blockIdx.z;
  in  += (size_t)z * R * C;
  out += (size_t)z * R * C;
  __shared__ float tile[64][65];
  const int t = threadIdx.x;
  const int r0 = blockIdx.y * 64, c0 = blockIdx.x * 64;
#pragma unroll
  for (int j = 0; j < 4; ++j) {
    const int r = j * 16 + (t >> 4);
    const int c = (t & 15) * 4;
    float4 v = *(const float4*)&in[(size_t)(r0 + r) * C + c0 + c];
    tile[r][c] = v.x; tile[r][c + 1] = v.y; tile[r][c + 2] = v.z; tile[r][c + 3] = v.w;
  }
  __syncthreads();
#pragma unroll
  for (int j = 0; j < 2; ++j) {
    const int wi = j * 256 + t;
    const int oc = wi >> 3;
    const int orr = (wi & 7) * 8;
    bf16x8 v;
#pragma unroll
    for (int u = 0; u < 8; ++u) v[u] = (bf16_t)tile[orr + u][oc];
    *(bf16x8*)&out[(size_t)(c0 + oc) * R + r0 + orr] = v;
  }
}

// bf16-input variant (for q^T).
__global__ __launch_bounds__(256) void wtransb_kernel(
    const bf16_t* __restrict__ in, bf16_t* __restrict__ out, int R, int C) {
  __shared__ float tile[64][65];
  const int t = threadIdx.x;
  const int r0 = blockIdx.y * 64, c0 = blockIdx.x * 64;
#pragma unroll
  for (int j = 0; j < 4; ++j) {
    const int r = j * 16 + (t >> 4);
    const int c = (t & 15) * 4;
    bf16x4 v = *(const bf16x4*)&in[(size_t)(r0 + r) * C + c0 + c];
    tile[r][c] = (float)v[0]; tile[r][c + 1] = (float)v[1];
    tile[r][c + 2] = (float)v[2]; tile[r][c + 3] = (float)v[3];
  }
  __syncthreads();
#pragma unroll
  for (int j = 0; j < 2; ++j) {
    const int wi = j * 256 + t;
    const int oc = wi >> 3;
    const int orr = (wi & 7) * 8;
    bf16x8 v;
#pragma unroll
    for (int u = 0; u < 8; ++u) v[u] = (bf16_t)tile[orr + u][oc];
    *(bf16x8*)&out[(size_t)(c0 + oc) * R + r0 + orr] = v;
  }
}

// ---------------------------------------------------------------------------
// LayerNorm over D=1024, f32 in -> bf16 out. One block (256 thr) per row.
__global__ __launch_bounds__(256) void ln_kernel(
    const float* __restrict__ x, const float* __restrict__ g,
    const float* __restrict__ b, bf16_t* __restrict__ out) {
  const int row = blockIdx.x;
  const int t = threadIdx.x;
  const float* xr = x + (size_t)row * DMODEL;
  float4 v = *(const float4*)&xr[t * 4];
  float s = v.x + v.y + v.z + v.w;
  float s2 = v.x * v.x + v.y * v.y + v.z * v.z + v.w * v.w;
#pragma unroll
  for (int off = 1; off < 64; off <<= 1) {
    s += __shfl_xor(s, off, 64);
    s2 += __shfl_xor(s2, off, 64);
  }
  __shared__ float ps[8];
  const int w = t >> 6;
  if ((t & 63) == 0) { ps[w] = s; ps[4 + w] = s2; }
  __syncthreads();
  s = ps[0] + ps[1] + ps[2] + ps[3];
  s2 = ps[4] + ps[5] + ps[6] + ps[7];
  const float mu = s / (float)DMODEL;
  const float var = s2 / (float)DMODEL - mu * mu;
  const float rstd = rsqrtf(var + 1e-5f);
  float4 gg = *(const float4*)&g[t * 4];
  float4 bb = *(const float4*)&b[t * 4];
  bf16x4 o;
  o[0] = (bf16_t)((v.x - mu) * rstd * gg.x + bb.x);
  o[1] = (bf16_t)((v.y - mu) * rstd * gg.y + bb.y);
  o[2] = (bf16_t)((v.z - mu) * rstd * gg.z + bb.z);
  o[3] = (bf16_t)((v.w - mu) * rstd * gg.w + bb.w);
  *(bf16x4*)&out[(size_t)row * DMODEL + t * 4] = o;
}

// ---------------------------------------------------------------------------
// Causal conv1d (k=4, left pad 3) + SiLU. bf16 in -> bf16 out.
__global__ __launch_bounds__(256) void conv_kernel(
    const bf16_t* __restrict__ xin, const float* __restrict__ cw,
    const float* __restrict__ cb, bf16_t* __restrict__ yb) {
  const size_t idx = (size_t)blockIdx.x * blockDim.x + threadIdx.x;
  const int row = (int)(idx >> 9);
  const int c0 = ((int)idx & 511) * 4;
  const bf16_t* xr = xin + (size_t)row * HDIM;
  const float w0 = cw[0], w1 = cw[1], w2 = cw[2], w3 = cw[3], bb = cb[0];
  float xm3 = 0.f, xm2 = 0.f, xm1 = 0.f;
  if (c0 > 0) {
    bf16x4 p = *(const bf16x4*)&xr[c0 - 4];
    xm3 = (float)p[1]; xm2 = (float)p[2]; xm1 = (float)p[3];
  }
  bf16x4 xv4 = *(const bf16x4*)&xr[c0];
  float x0 = (float)xv4[0], x1 = (float)xv4[1], x2 = (float)xv4[2], x3 = (float)xv4[3];
  float y0 = w0 * xm3 + w1 * xm2 + w2 * xm1 + w3 * x0 + bb;
  float y1 = w0 * xm2 + w1 * xm1 + w2 * x0 + w3 * x1 + bb;
  float y2 = w0 * xm1 + w1 * x0 + w2 * x1 + w3 * x2 + bb;
  float y3 = w0 * x0 + w1 * x1 + w2 * x2 + w3 * x3 + bb;
  bf16x4 yb4;
  yb4[0] = (bf16_t)siluf_(y0); yb4[1] = (bf16_t)siluf_(y1);
  yb4[2] = (bf16_t)siluf_(y2); yb4[3] = (bf16_t)siluf_(y3);
  *(bf16x4*)&yb[(size_t)row * HDIM + c0] = yb4;
}

// ---------------------------------------------------------------------------
// h_t + GroupNorm(8 groups of 256) + skip + silu-gate. One block per row.
__global__ __launch_bounds__(256) void hgn_kernel(
    const bf16_t* __restrict__ o_pre, const bf16_t* __restrict__ q,
    const float* __restrict__ c_t, const float* __restrict__ denomf,
    const bf16_t* __restrict__ skip, const bf16_t* __restrict__ upr,
    const float* __restrict__ gn_g, const float* __restrict__ gn_b,
    float* __restrict__ h_out, bf16_t* __restrict__ act_out) {
  const int row = blockIdx.x;
  const int t = threadIdx.x;
  const size_t base = (size_t)row * HDIM + t * 8;
  const int i0 = t * 8;
  bf16x8 o8 = *(const bf16x8*)&o_pre[base];
  bf16x8 q8 = *(const bf16x8*)&q[base];
  float h[8];
  float s = 0.f, s2 = 0.f;
#pragma unroll
  for (int j = 0; j < 2; ++j) {
    float4 cv = *(const float4*)&c_t[base + j * 4];
#pragma unroll
    for (int u = 0; u < 4; ++u) {
      const int k = j * 4 + u;
      float hv = sigmoidf_((float)o8[k]) * ((const float*)&cv)[u] *
                 (float)q8[k] / denomf[i0 + k];
      h[k] = hv;
      s += hv;
      s2 += hv * hv;
    }
  }
#pragma unroll
  for (int off = 1; off < 32; off <<= 1) {
    s += __shfl_xor(s, off, 64);
    s2 += __shfl_xor(s2, off, 64);
  }
  const float mu = s / 256.f;
  const float var = s2 / 256.f - mu * mu;
  const float rstd = rsqrtf(var + 1e-5f);
  float4 h0 = {h[0], h[1], h[2], h[3]};
  float4 h1 = {h[4], h[5], h[6], h[7]};
  *(float4*)&h_out[base] = h0;
  *(float4*)&h_out[base + 4] = h1;
  bf16x8 sk8 = *(const bf16x8*)&skip[base];
  bf16x8 up8 = *(const bf16x8*)&upr[base];
  bf16x8 a8;
#pragma unroll
  for (int j = 0; j < 2; ++j) {
    float4 gv = *(const float4*)&gn_g[i0 + j * 4];
    float4 bv = *(const float4*)&gn_b[i0 + j * 4];
#pragma unroll
    for (int u = 0; u < 4; ++u) {
      const int k = j * 4 + u;
      float y = (h[k] - mu) * rstd * ((const float*)&gv)[u] + ((const float*)&bv)[u];
      y = (y + (float)sk8[k]) * siluf_((float)up8[k]);
      a8[k] = (bf16_t)y;
    }
  }
  *(bf16x8*)&act_out[base] = a8;
}

// ---------------------------------------------------------------------------
// 128^2 / BK=32 GEMM (kept for small block-diagonal qkv).
template <int OUTMODE, bool RES>
__global__ __launch_bounds__(256) void gemm_kernel(
    const bf16_t* __restrict__ A, int lda, const bf16_t* __restrict__ Bt, int ldb,
    const float* __restrict__ bias, float* __restrict__ C, bf16_t* __restrict__ Cb,
    int ldc, const float* __restrict__ res, int ldres, int K, float scale,
    int zA, long long zB, int zBias, int zC) {
  const int z = blockIdx.z;
  A += (size_t)z * zA;
  Bt += (size_t)z * zB;
  if (bias) bias += (size_t)z * zBias;
  if (OUTMODE == 0) C += (size_t)z * zC; else Cb += (size_t)z * zC;
  const int brow = blockIdx.y * 128;
  const int bcol = blockIdx.x * 128;
  __shared__ bf16_t As[128 * 32];
  __shared__ bf16_t Bs[128 * 32];
  const int tid = threadIdx.x;
  const int w = tid >> 6, l = tid & 63;
  const int wr = w >> 1, wc = w & 1;
  const int lr = l & 15, kg = l >> 4;
  const int l4 = l & 3, ld4 = l >> 2;

  f32x4 acc[4][4];
  const f32x4 fzero = {0.f, 0.f, 0.f, 0.f};
#pragma unroll
  for (int m = 0; m < 4; ++m)
#pragma unroll
    for (int n = 0; n < 4; ++n) acc[m][n] = fzero;

  for (int kt = 0; kt < K; kt += 32) {
#pragma unroll
    for (int j = 0; j < 2; ++j) {
      const int rowX = w * 32 + j * 16 + ld4;
      gload_lds16(A + (size_t)(brow + rowX) * lda + kt + l4 * 8, &As[w * 1024 + j * 512]);
      gload_lds16(Bt + (size_t)(bcol + rowX) * ldb + kt + l4 * 8, &Bs[w * 1024 + j * 512]);
    }
    __syncthreads();
    bf16x8 a[4], b[4];
#pragma unroll
    for (int m = 0; m < 4; ++m)
      a[m] = *(const bf16x8*)&As[(wr * 64 + m * 16 + lr) * 32 + kg * 8];
#pragma unroll
    for (int n = 0; n < 4; ++n)
      b[n] = *(const bf16x8*)&Bs[(wc * 64 + n * 16 + lr) * 32 + kg * 8];
#pragma unroll
    for (int m = 0; m < 4; ++m)
#pragma unroll
      for (int n = 0; n < 4; ++n)
        acc[m][n] = __builtin_amdgcn_mfma_f32_16x16x32_bf16(a[m], b[n], acc[m][n], 0, 0, 0);
    __syncthreads();
  }

#pragma unroll
  for (int m = 0; m < 4; ++m) {
    const int row0 = brow + wr * 64 + m * 16 + kg * 4;
#pragma unroll
    for (int n = 0; n < 4; ++n) {
      const int col = bcol + wc * 64 + n * 16 + lr;
      const float bv = bias ? bias[col] : 0.f;
#pragma unroll
      for (int r = 0; r < 4; ++r) {
        const int row = row0 + r;
        float v = (acc[m][n][r] + bv) * scale;
        if (RES) v += res[(size_t)row * ldres + col];
        if (OUTMODE == 0) C[(size_t)row * ldc + col] = v;
        else Cb[(size_t)row * ldc + col] = (bf16_t)v;
      }
    }
  }
}

// LDS swizzle helpers for the khalf engine:
//   32-elem (64B) rows, 4x16B slots; slot' = kg ^ ((row>>1)&3) (2-way, free).
//   Staging (linear dest granule L): row=L>>2, source slot = (L&3)^((L>>3)&3).
#define SWZ_RD(r, kg) (((kg) ^ (((r) >> 1) & 3)) * 8)

// ---------------------------------------------------------------------------
// 256^2 GEMM, k-half phase engine. LDS [2dbuf][2khalf][256][32] per operand.
template <int OUTMODE /*0=f32,2=bf16*/, bool RES>
__global__ __launch_bounds__(512, 2) void gemm256_kernel(
    const bf16_t* __restrict__ A, int lda, const bf16_t* __restrict__ Bt, int ldb,
    const float* __restrict__ bias, float* __restrict__ C, bf16_t* __restrict__ Cb,
    int ldc, const float* __restrict__ res, int ldres, int K, float scale,
    long long zA, long long zB, long long zC) {
  const int z = blockIdx.z;
  A += (size_t)z * zA;
  Bt += (size_t)z * zB;
  if (OUTMODE == 0) C += (size_t)z * zC; else Cb += (size_t)z * zC;

  const int nwg = gridDim.x * gridDim.y;
  const int lin2 = xcd_swz(blockIdx.y * gridDim.x + blockIdx.x, nwg);
  const int bx = lin2 % gridDim.x, by = lin2 / gridDim.x;
  const int brow = by * 256, bcol = bx * 256;

  __shared__ bf16_t As[2][2][256 * 32];
  __shared__ bf16_t Bs[2][2][256 * 32];

  const int tid = threadIdx.x;
  const int l = tid & 63;
  const int w = tid >> 6;
  const int wr = w >> 2, wn = w & 3;  // 2 (M) x 4 (N) waves
  const int lr = l & 15, kg = l >> 4;

  f32x4 acc[8][4];
  const f32x4 fzero = {0.f, 0.f, 0.f, 0.f};
#pragma unroll
  for (int m = 0; m < 8; ++m)
#pragma unroll
    for (int n = 0; n < 4; ++n) acc[m][n] = fzero;

  const int NT = K >> 6;
  const bf16_t* Ag = A + (size_t)brow * lda;
  const bf16_t* Bg = Bt + (size_t)bcol * ldb;

  auto stageA = [&](int d, int kh, int kbase) {
#pragma unroll
    for (int j = 0; j < 2; ++j) {
      const int L = j * 512 + tid;
      const int row = L >> 2;
      const int s = (L & 3) ^ ((L >> 3) & 3);
      gload_lds16(Ag + (size_t)row * lda + kbase + kh * 32 + s * 8,
                  (char*)&As[d][kh][0] + L * 16);
    }
  };
  auto stageB = [&](int d, int kh, int kbase) {
#pragma unroll
    for (int j = 0; j < 2; ++j) {
      const int L = j * 512 + tid;
      const int row = L >> 2;
      const int s = (L & 3) ^ ((L >> 3) & 3);
      gload_lds16(Bg + (size_t)row * ldb + kbase + kh * 32 + s * 8,
                  (char*)&Bs[d][kh][0] + L * 16);
    }
  };

  // prologue: tile 0 halves in order A0,B0,A1,B1 (8 loads outstanding)
  stageA(0, 0, 0); stageB(0, 0, 0); stageA(0, 1, 0); stageB(0, 1, 0);

  for (int t = 0; t < NT; ++t) {
    const int d = t & 1;
    const int kn = (t + 1) * 64;
    const bool st = (t + 1 < NT);
    bf16x8 a[4], b[4];

    // ---- kk = 0 ----
    asm volatile("s_waitcnt vmcnt(4)" ::: "memory");
    __builtin_amdgcn_s_barrier();
    if (st) stageA(d ^ 1, 0, kn);
#pragma unroll
    for (int n = 0; n < 4; ++n) {
      const int r = wn * 64 + n * 16 + lr;
      b[n] = *(const bf16x8*)&Bs[d][0][r * 32 + SWZ_RD(r, kg)];
    }
#pragma unroll
    for (int mm = 0; mm < 4; ++mm) {
      const int r = wr * 128 + mm * 16 + lr;
      a[mm] = *(const bf16x8*)&As[d][0][r * 32 + SWZ_RD(r, kg)];
    }
    __builtin_amdgcn_s_setprio(1);
#pragma unroll
    for (int mm = 0; mm < 4; ++mm)
#pragma unroll
      for (int n = 0; n < 4; ++n)
        acc[mm][n] = __builtin_amdgcn_mfma_f32_16x16x32_bf16(a[mm], b[n], acc[mm][n], 0, 0, 0);
    __builtin_amdgcn_s_setprio(0);
    if (st) stageB(d ^ 1, 0, kn);
#pragma unroll
    for (int mm = 0; mm < 4; ++mm) {
      const int r = wr * 128 + (4 + mm) * 16 + lr;
      a[mm] = *(const bf16x8*)&As[d][0][r * 32 + SWZ_RD(r, kg)];
    }
    __builtin_amdgcn_s_setprio(1);
#pragma unroll
    for (int mm = 0; mm < 4; ++mm)
#pragma unroll
      for (int n = 0; n < 4; ++n)
        acc[4 + mm][n] = __builtin_amdgcn_mfma_f32_16x16x32_bf16(a[mm], b[n], acc[4 + mm][n], 0, 0, 0);
    __builtin_amdgcn_s_setprio(0);

    // ---- kk = 1 ----
    if (t == NT - 1) asm volatile("s_waitcnt vmcnt(0)" ::: "memory");
    else             asm volatile("s_waitcnt vmcnt(4)" ::: "memory");
    __builtin_amdgcn_s_barrier();
    if (st) stageA(d ^ 1, 1, kn);
#pragma unroll
    for (int n = 0; n < 4; ++n) {
      const int r = wn * 64 + n * 16 + lr;
      b[n] = *(const bf16x8*)&Bs[d][1][r * 32 + SWZ_RD(r, kg)];
    }
#pragma unroll
    for (int mm = 0; mm < 4; ++mm) {
      const int r = wr * 128 + mm * 16 + lr;
      a[mm] = *(const bf16x8*)&As[d][1][r * 32 + SWZ_RD(r, kg)];
    }
    __builtin_amdgcn_s_setprio(1);
#pragma unroll
    for (int mm = 0; mm < 4; ++mm)
#pragma unroll
      for (int n = 0; n < 4; ++n)
        acc[mm][n] = __builtin_amdgcn_mfma_f32_16x16x32_bf16(a[mm], b[n], acc[mm][n], 0, 0, 0);
    __builtin_amdgcn_s_setprio(0);
    if (st) stageB(d ^ 1, 1, kn);
#pragma unroll
    for (int mm = 0; mm < 4; ++mm) {
      const int r = wr * 128 + (4 + mm) * 16 + lr;
      a[mm] = *(const bf16x8*)&As[d][1][r * 32 + SWZ_RD(r, kg)];
    }
    __builtin_amdgcn_s_setprio(1);
#pragma unroll
    for (int mm = 0; mm < 4; ++mm)
#pragma unroll
      for (int n = 0; n < 4; ++n)
        acc[4 + mm][n] = __builtin_amdgcn_mfma_f32_16x16x32_bf16(a[mm], b[n], acc[4 + mm][n], 0, 0, 0);
    __builtin_amdgcn_s_setprio(0);
  }

#pragma unroll
  for (int m = 0; m < 8; ++m) {
    const int row0 = brow + wr * 128 + m * 16 + kg * 4;
#pragma unroll
    for (int n = 0; n < 4; ++n) {
      const int col = bcol + wn * 64 + n * 16 + lr;
      const float bvv = bias ? bias[col] : 0.f;
#pragma unroll
      for (int r = 0; r < 4; ++r) {
        const int row = row0 + r;
        float v = (acc[m][n][r] + bvv) * scale;
        if (RES) v += res[(size_t)row * ldres + col];
        if (OUTMODE == 0) C[(size_t)row * ldc + col] = v;
        else Cb[(size_t)row * ldc + col] = (bf16_t)v;
      }
    }
  }
}

// ---------------------------------------------------------------------------
// 256x128 single-B khalf engine (for down projection: fills all CUs at N=1024).
// Stage order per tile: A-kh(2 loads), B-kh(1) => vmcnt(3)/(3)/(0 tail).
template <int OUTMODE, bool RES>
__global__ __launch_bounds__(512, 2) void gemm256n128_kernel(
    const bf16_t* __restrict__ A, int lda, const bf16_t* __restrict__ Bt, int ldb,
    const float* __restrict__ bias, float* __restrict__ C, bf16_t* __restrict__ Cb,
    int ldc, const float* __restrict__ res, int ldres, int K, float scale) {
  const int nwg = gridDim.x * gridDim.y;
  const int lin2 = xcd_swz(blockIdx.y * gridDim.x + blockIdx.x, nwg);
  const int bx = lin2 % gridDim.x, by = lin2 / gridDim.x;
  const int brow = by * 256, bcol = bx * 128;

  __shared__ bf16_t As[2][2][256 * 32];
  __shared__ bf16_t Bs[2][2][128 * 32];

  const int tid = threadIdx.x;
  const int l = tid & 63;
  const int w = tid >> 6;
  const int wr = w >> 2, wn = w & 3;
  const int lr = l & 15, kg = l >> 4;

  f32x4 acc[8][2];
  const f32x4 fzero = {0.f, 0.f, 0.f, 0.f};
#pragma unroll
  for (int m = 0; m < 8; ++m)
#pragma unroll
    for (int n = 0; n < 2; ++n) acc[m][n] = fzero;

  const int NT = K >> 6;
  const bf16_t* Ag = A + (size_t)brow * lda;
  const bf16_t* Bg = Bt + (size_t)bcol * ldb;

  auto stageA = [&](int d, int kh, int kbase) {
#pragma unroll
    for (int j = 0; j < 2; ++j) {
      const int L = j * 512 + tid;
      const int row = L >> 2;
      const int s = (L & 3) ^ ((L >> 3) & 3);
      gload_lds16(Ag + (size_t)row * lda + kbase + kh * 32 + s * 8,
                  (char*)&As[d][kh][0] + L * 16);
    }
  };
  auto stageB = [&](int d, int kh, int kbase) {
    const int L = tid;
    const int row = L >> 2;
    const int s = (L & 3) ^ ((L >> 3) & 3);
    gload_lds16(Bg + (size_t)row * ldb + kbase + kh * 32 + s * 8,
                (char*)&Bs[d][kh][0] + L * 16);
  };

  stageA(0, 0, 0); stageB(0, 0, 0); stageA(0, 1, 0); stageB(0, 1, 0);

  for (int t = 0; t < NT; ++t) {
    const int d = t & 1;
    const int kn = (t + 1) * 64;
    const bool st = (t + 1 < NT);
    bf16x8 a[4], b[2];

#pragma unroll
    for (int kk = 0; kk < 2; ++kk) {
      if (kk == 0 || t < NT - 1) asm volatile("s_waitcnt vmcnt(3)" ::: "memory");
      else                       asm volatile("s_waitcnt vmcnt(0)" ::: "memory");
      __builtin_amdgcn_s_barrier();
      if (st) stageA(d ^ 1, kk, kn);
#pragma unroll
      for (int n = 0; n < 2; ++n) {
        const int r = wn * 32 + n * 16 + lr;
        b[n] = *(const bf16x8*)&Bs[d][kk][r * 32 + SWZ_RD(r, kg)];
      }
#pragma unroll
      for (int mm = 0; mm < 4; ++mm) {
        const int r = wr * 128 + mm * 16 + lr;
        a[mm] = *(const bf16x8*)&As[d][kk][r * 32 + SWZ_RD(r, kg)];
      }
      __builtin_amdgcn_s_setprio(1);
#pragma unroll
      for (int mm = 0; mm < 4; ++mm)
#pragma unroll
        for (int n = 0; n < 2; ++n)
          acc[mm][n] = __builtin_amdgcn_mfma_f32_16x16x32_bf16(a[mm], b[n], acc[mm][n], 0, 0, 0);
      __builtin_amdgcn_s_setprio(0);
      if (st) stageB(d ^ 1, kk, kn);
#pragma unroll
      for (int mm = 0; mm < 4; ++mm) {
        const int r = wr * 128 + (4 + mm) * 16 + lr;
        a[mm] = *(const bf16x8*)&As[d][kk][r * 32 + SWZ_RD(r, kg)];
      }
      __builtin_amdgcn_s_setprio(1);
#pragma unroll
      for (int mm = 0; mm < 4; ++mm)
#pragma unroll
        for (int n = 0; n < 2; ++n)
          acc[4 + mm][n] = __builtin_amdgcn_mfma_f32_16x16x32_bf16(a[mm], b[n], acc[4 + mm][n], 0, 0, 0);
      __builtin_amdgcn_s_setprio(0);
    }
  }

#pragma unroll
  for (int m = 0; m < 8; ++m) {
    const int row0 = brow + wr * 128 + m * 16 + kg * 4;
#pragma unroll
    for (int n = 0; n < 2; ++n) {
      const int col = bcol + wn * 32 + n * 16 + lr;
      const float bvv = bias ? bias[col] : 0.f;
#pragma unroll
      for (int r = 0; r < 4; ++r) {
        const int row = row0 + r;
        float v = (acc[m][n][r] + bvv) * scale;
        if (RES) v += res[(size_t)row * ldres + col];
        if (OUTMODE == 0) C[(size_t)row * ldc + col] = v;
        else Cb[(size_t)row * ldc + col] = (bf16_t)v;
      }
    }
  }
}

// ---------------------------------------------------------------------------
// 256x128 dual-B khalf engine + fused mLSTM gate epilogue.
// Stage order per tile: A-kh(2), Bi-kh(1), Bf-kh(1) => vmcnt(4)/(4)/(0 tail).
__global__ __launch_bounds__(512, 2) void ifgate256_kernel(
    const bf16_t* __restrict__ A,
    const bf16_t* __restrict__ Bi, const bf16_t* __restrict__ Bf,
    const float* __restrict__ bi, const float* __restrict__ bfv,
    const float* __restrict__ m_prev, const float* __restrict__ c_prev,
    const float* __restrict__ n_prev,
    const bf16_t* __restrict__ vb, const bf16_t* __restrict__ kb,
    float* __restrict__ m_out, float* __restrict__ c_out, float* __restrict__ n_out) {
  const int nwg = gridDim.x * gridDim.y;
  const int lin2 = xcd_swz(blockIdx.y * gridDim.x + blockIdx.x, nwg);
  const int bx = lin2 % gridDim.x, by = lin2 / gridDim.x;
  const int brow = by * 256, bcol = bx * 128;

  __shared__ bf16_t As[2][2][256 * 32];
  __shared__ bf16_t Bis[2][2][128 * 32];
  __shared__ bf16_t Bfs[2][2][128 * 32];

  const int tid = threadIdx.x;
  const int l = tid & 63;
  const int w = tid >> 6;
  const int wr = w >> 2, wn = w & 3;
  const int lr = l & 15, kg = l >> 4;

  f32x4 acci[8][2], accf[8][2];
  const f32x4 fzero = {0.f, 0.f, 0.f, 0.f};
#pragma unroll
  for (int m = 0; m < 8; ++m)
#pragma unroll
    for (int n = 0; n < 2; ++n) { acci[m][n] = fzero; accf[m][n] = fzero; }

  const int NT = HDIM >> 6;
  const bf16_t* Ag = A + (size_t)brow * HDIM;
  const bf16_t* Big = Bi + (size_t)bcol * HDIM;
  const bf16_t* Bfg = Bf + (size_t)bcol * HDIM;

  auto stageA = [&](int d, int kh, int kbase) {
#pragma unroll
    for (int j = 0; j < 2; ++j) {
      const int L = j * 512 + tid;
      const int row = L >> 2;
      const int s = (L & 3) ^ ((L >> 3) & 3);
      gload_lds16(Ag + (size_t)row * HDIM + kbase + kh * 32 + s * 8,
                  (char*)&As[d][kh][0] + L * 16);
    }
  };
  auto stageBB = [&](int d, int kh, int kbase) {
    const int L = tid;
    const int row = L >> 2;
    const int s = (L & 3) ^ ((L >> 3) & 3);
    gload_lds16(Big + (size_t)row * HDIM + kbase + kh * 32 + s * 8,
                (char*)&Bis[d][kh][0] + L * 16);
    gload_lds16(Bfg + (size_t)row * HDIM + kbase + kh * 32 + s * 8,
                (char*)&Bfs[d][kh][0] + L * 16);
  };

  stageA(0, 0, 0); stageBB(0, 0, 0); stageA(0, 1, 0); stageBB(0, 1, 0);

  for (int t = 0; t < NT; ++t) {
    const int d = t & 1;
    const int kn = (t + 1) * 64;
    const bool st = (t + 1 < NT);
    bf16x8 a[4], b1[2], b2[2];

#pragma unroll
    for (int kk = 0; kk < 2; ++kk) {
      if (kk == 0 || t < NT - 1) asm volatile("s_waitcnt vmcnt(4)" ::: "memory");
      else                       asm volatile("s_waitcnt vmcnt(0)" ::: "memory");
      __builtin_amdgcn_s_barrier();
      if (st) stageA(d ^ 1, kk, kn);
#pragma unroll
      for (int n = 0; n < 2; ++n) {
        const int r = wn * 32 + n * 16 + lr;
        const int eo = r * 32 + SWZ_RD(r, kg);
        b1[n] = *(const bf16x8*)&Bis[d][kk][eo];
        b2[n] = *(const bf16x8*)&Bfs[d][kk][eo];
      }
#pragma unroll
      for (int mm = 0; mm < 4; ++mm) {
        const int r = wr * 128 + mm * 16 + lr;
        a[mm] = *(const bf16x8*)&As[d][kk][r * 32 + SWZ_RD(r, kg)];
      }
      __builtin_amdgcn_s_setprio(1);
#pragma unroll
      for (int mm = 0; mm < 4; ++mm)
#pragma unroll
        for (int n = 0; n < 2; ++n) {
          acci[mm][n] = __builtin_amdgcn_mfma_f32_16x16x32_bf16(a[mm], b1[n], acci[mm][n], 0, 0, 0);
          accf[mm][n] = __builtin_amdgcn_mfma_f32_16x16x32_bf16(a[mm], b2[n], accf[mm][n], 0, 0, 0);
        }
      __builtin_amdgcn_s_setprio(0);
      if (st) stageBB(d ^ 1, kk, kn);
#pragma unroll
      for (int mm = 0; mm < 4; ++mm) {
        const int r = wr * 128 + (4 + mm) * 16 + lr;
        a[mm] = *(const bf16x8*)&As[d][kk][r * 32 + SWZ_RD(r, kg)];
      }
      __builtin_amdgcn_s_setprio(1);
#pragma unroll
      for (int mm = 0; mm < 4; ++mm)
#pragma unroll
        for (int n = 0; n < 2; ++n) {
          acci[4 + mm][n] = __builtin_amdgcn_mfma_f32_16x16x32_bf16(a[mm], b1[n], acci[4 + mm][n], 0, 0, 0);
          accf[4 + mm][n] = __builtin_amdgcn_mfma_f32_16x16x32_bf16(a[mm], b2[n], accf[4 + mm][n], 0, 0, 0);
        }
      __builtin_amdgcn_s_setprio(0);
    }
  }

#pragma unroll
  for (int m = 0; m < 8; ++m) {
    const int row0 = brow + wr * 128 + m * 16 + kg * 4;
#pragma unroll
    for (int n = 0; n < 2; ++n) {
      const int col = bcol + wn * 32 + n * 16 + lr;
      const float biv = bi[col], bfvv = bfv[col];
#pragma unroll
      for (int r = 0; r < 4; ++r) {
        const int row = row0 + r;
        const size_t idx = (size_t)row * HDIM + col;
        const float it = acci[m][n][r] + biv;
        const float ft = accf[m][n][r] + bfvv;
        const float m1 = m_prev[idx];
        const float mt = fmaxf(ft + m1, it);
        const float ig = __expf(it - mt);
        const float fg = __expf(ft + m1 - mt);
        const float v1 = (float)vb[idx], k1 = (float)kb[idx];
        m_out[idx] = mt;
        c_out[idx] = fg * c_prev[idx] + ig * (v1 * k1);
        n_out[idx] = fg * n_prev[idx] + ig * k1;
      }
    }
  }
}

// ---------------------------------------------------------------------------
// denom reduce: dmax[i] = max_j |sum_z part[z][i][j]| (4 split-K parts)
__global__ __launch_bounds__(256) void denom_reduce_kernel(
    const float* __restrict__ part, float* __restrict__ dmaxf) {
  const int i = blockIdx.x;
  const int t = threadIdx.x;
  float vmax = 0.f;
#pragma unroll
  for (int u = 0; u < 8; ++u) {
    const int j = u * 256 + t;
    float s = 0.f;
#pragma unroll
    for (int zz = 0; zz < 4; ++zz)
      s += part[(size_t)zz * HDIM * HDIM + (size_t)i * HDIM + j];
    vmax = fmaxf(vmax, fabsf(s));
  }
#pragma unroll
  for (int off = 1; off < 64; off <<= 1) vmax = fmaxf(vmax, __shfl_xor(vmax, off, 64));
  __shared__ float ps[4];
  if ((t & 63) == 0) ps[t >> 6] = vmax;
  __syncthreads();
  if (t == 0) dmaxf[i] = fmaxf(fmaxf(ps[0], ps[1]), fmaxf(ps[2], ps[3]));
}

// ---------------------------------------------------------------------------
extern "C" void kernel_launch(void* const* d_in, const int* in_sizes, int n_in,
                              void* d_out, int out_size, void* d_ws, size_t ws_size,
                              hipStream_t stream) {
  (void)in_sizes; (void)n_in; (void)out_size; (void)ws_size;
  const float* x      = (const float*)d_in[0];
  const float* ln_g   = (const float*)d_in[1];
  const float* ln_b   = (const float*)d_in[2];
  const float* Wupl   = (const float*)d_in[3];
  const float* bupl   = (const float*)d_in[4];
  const float* Wupr   = (const float*)d_in[5];
  const float* bupr   = (const float*)d_in[6];
  const float* conv_w = (const float*)d_in[7];
  const float* conv_b = (const float*)d_in[8];
  const float* Wskip  = (const float*)d_in[9];
  const float* bskip  = (const float*)d_in[10];
  const float* Wq     = (const float*)d_in[11];
  const float* bq     = (const float*)d_in[12];
  const float* Wk     = (const float*)d_in[13];
  const float* bk     = (const float*)d_in[14];
  const float* Wv     = (const float*)d_in[15];
  const float* bv     = (const float*)d_in[16];
  const float* Wi     = (const float*)d_in[17];
  const float* bi     = (const float*)d_in[18];
  const float* Wf     = (const float*)d_in[19];
  const float* bf_    = (const float*)d_in[20];
  const float* Wo     = (const float*)d_in[21];
  const float* bo     = (const float*)d_in[22];
  const float* gn_g   = (const float*)d_in[23];
  const float* gn_b   = (const float*)d_in[24];
  const float* Wdown  = (const float*)d_in[25];
  const float* bdown  = (const float*)d_in[26];
  const float* c_prev = (const float*)d_in[27];
  const float* n_prev = (const float*)d_in[28];
  const float* m_prev = (const float*)d_in[29];

  float* out_final = (float*)d_out;
  float* out_h = out_final + (size_t)B_ROWS * DMODEL;
  float* out_c = out_h + (size_t)B_ROWS * HDIM;
  float* out_n = out_c + (size_t)B_ROWS * HDIM;
  float* out_m = out_n + (size_t)B_ROWS * HDIM;

  char* ws = (char*)d_ws;
  size_t off = 0;
  auto alloc = [&](size_t bytes) -> void* {
    off = (off + 255) & ~(size_t)255;
    void* p = ws + off;
    off += bytes;
    return p;
  };
  const size_t BH = (size_t)B_ROWS * HDIM;
  const size_t BD = (size_t)B_ROWS * DMODEL;

  bf16_t* WuplT = (bf16_t*)alloc((size_t)DMODEL * HDIM * 2);
  bf16_t* WuprT = (bf16_t*)alloc((size_t)DMODEL * HDIM * 2);
  bf16_t* WskipT = (bf16_t*)alloc((size_t)HDIM * HDIM * 2);
  bf16_t* WiT = (bf16_t*)alloc((size_t)HDIM * HDIM * 2);
  bf16_t* WfT = (bf16_t*)alloc((size_t)HDIM * HDIM * 2);
  bf16_t* WoT = (bf16_t*)alloc((size_t)HDIM * HDIM * 2);
  bf16_t* WdownT = (bf16_t*)alloc((size_t)HDIM * DMODEL * 2);
  bf16_t* WqT = (bf16_t*)alloc((size_t)8 * 256 * 256 * 2);
  bf16_t* WkT = (bf16_t*)alloc((size_t)8 * 256 * 256 * 2);
  bf16_t* WvT = (bf16_t*)alloc((size_t)8 * 256 * 256 * 2);
  bf16_t* xnorm_b = (bf16_t*)alloc(BD * 2);
  bf16_t* xupl_b = (bf16_t*)alloc(BH * 2);
  bf16_t* xupr_b = (bf16_t*)alloc(BH * 2);
  bf16_t* xconv_b = (bf16_t*)alloc(BH * 2);
  bf16_t* xskip_b = (bf16_t*)alloc(BH * 2);
  bf16_t* o_b = (bf16_t*)alloc(BH * 2);
  bf16_t* q_b = (bf16_t*)alloc(BH * 2);
  bf16_t* k_b = (bf16_t*)alloc(BH * 2);
  bf16_t* v_b = (bf16_t*)alloc(BH * 2);
  bf16_t* qT_b = (bf16_t*)alloc(BH * 2);
  bf16_t* nT_b = (bf16_t*)alloc(BH * 2);
  bf16_t* act_b = (bf16_t*)alloc(BH * 2);
  float*  part = (float*)alloc((size_t)4 * HDIM * HDIM * 4);
  float*  dmaxf = (float*)alloc(HDIM * 4);

  // ---- weights: transpose + convert to bf16 (N x K layout)
  wtrans_kernel<<<dim3(HDIM / 64, DMODEL / 64, 1), 256, 0, stream>>>(Wupl, WuplT, DMODEL, HDIM);
  wtrans_kernel<<<dim3(HDIM / 64, DMODEL / 64, 1), 256, 0, stream>>>(Wupr, WuprT, DMODEL, HDIM);
  wtrans_kernel<<<dim3(HDIM / 64, HDIM / 64, 1), 256, 0, stream>>>(Wskip, WskipT, HDIM, HDIM);
  wtrans_kernel<<<dim3(HDIM / 64, HDIM / 64, 1), 256, 0, stream>>>(Wi, WiT, HDIM, HDIM);
  wtrans_kernel<<<dim3(HDIM / 64, HDIM / 64, 1), 256, 0, stream>>>(Wf, WfT, HDIM, HDIM);
  wtrans_kernel<<<dim3(HDIM / 64, HDIM / 64, 1), 256, 0, stream>>>(Wo, WoT, HDIM, HDIM);
  wtrans_kernel<<<dim3(DMODEL / 64, HDIM / 64, 1), 256, 0, stream>>>(Wdown, WdownT, HDIM, DMODEL);
  wtrans_kernel<<<dim3(4, 4, 8), 256, 0, stream>>>(Wq, WqT, 256, 256);
  wtrans_kernel<<<dim3(4, 4, 8), 256, 0, stream>>>(Wk, WkT, 256, 256);
  wtrans_kernel<<<dim3(4, 4, 8), 256, 0, stream>>>(Wv, WvT, 256, 256);

  // ---- layernorm
  ln_kernel<<<B_ROWS, 256, 0, stream>>>(x, ln_g, ln_b, xnorm_b);

  // ---- up projections (bf16 outputs)
  gemm256_kernel<2, false><<<dim3(HDIM / 256, B_ROWS / 256, 1), 512, 0, stream>>>(
      xnorm_b, DMODEL, WuplT, DMODEL, bupl, nullptr, xupl_b, HDIM, nullptr, 0,
      DMODEL, 1.f, 0, 0, 0);
  gemm256_kernel<2, false><<<dim3(HDIM / 256, B_ROWS / 256, 1), 512, 0, stream>>>(
      xnorm_b, DMODEL, WuprT, DMODEL, bupr, nullptr, xupr_b, HDIM, nullptr, 0,
      DMODEL, 1.f, 0, 0, 0);

  // ---- causal conv + silu
  conv_kernel<<<(unsigned)(BH / 4 / 256), 256, 0, stream>>>(xupl_b, conv_w, conv_b, xconv_b);

  // ---- skip and o projections (bf16 out)
  gemm256_kernel<2, false><<<dim3(HDIM / 256, B_ROWS / 256, 1), 512, 0, stream>>>(
      xconv_b, HDIM, WskipT, HDIM, bskip, nullptr, xskip_b, HDIM, nullptr, 0,
      HDIM, 1.f, 0, 0, 0);
  gemm256_kernel<2, false><<<dim3(HDIM / 256, B_ROWS / 256, 1), 512, 0, stream>>>(
      xupl_b, HDIM, WoT, HDIM, bo, nullptr, o_b, HDIM, nullptr, 0,
      HDIM, 1.f, 0, 0, 0);

  // ---- block-diagonal q, k, v (bf16 outs) — small K, 128^2 kernel
  gemm_kernel<2, false><<<dim3(2, B_ROWS / 128, 8), 256, 0, stream>>>(
      xconv_b, HDIM, WqT, 256, bq, nullptr, q_b, HDIM, nullptr, 0,
      256, 1.f, 256, 256 * 256, 256, 256);
  gemm_kernel<2, false><<<dim3(2, B_ROWS / 128, 8), 256, 0, stream>>>(
      xconv_b, HDIM, WkT, 256, bk, nullptr, k_b, HDIM, nullptr, 0,
      256, 0.0625f, 256, 256 * 256, 256, 256);
  gemm_kernel<2, false><<<dim3(2, B_ROWS / 128, 8), 256, 0, stream>>>(
      xupl_b, HDIM, WvT, 256, bv, nullptr, v_b, HDIM, nullptr, 0,
      256, 1.f, 256, 256 * 256, 256, 256);

  // ---- i/f dual GEMM + fused gate -> m_t, c_t, n_t
  ifgate256_kernel<<<dim3(HDIM / 128, B_ROWS / 256, 1), 512, 0, stream>>>(
      xconv_b, WiT, WfT, bi, bf_, m_prev, c_prev, n_prev, v_b, k_b,
      out_m, out_c, out_n);

  // ---- transpose q and n_t to k-major bf16 for the denom GEMM
  wtransb_kernel<<<dim3(HDIM / 64, B_ROWS / 64, 1), 256, 0, stream>>>(q_b, qT_b, B_ROWS, HDIM);
  wtrans_kernel<<<dim3(HDIM / 64, B_ROWS / 64, 1), 256, 0, stream>>>(out_n, nT_b, B_ROWS, HDIM);

  // ---- denom: split-K(4) GEMM partials + reduce
  gemm256_kernel<0, false><<<dim3(HDIM / 256, HDIM / 256, 4), 512, 0, stream>>>(
      nT_b, B_ROWS, qT_b, B_ROWS, nullptr, part, nullptr, HDIM, nullptr, 0,
      2048, 1.f, 2048, 2048, (long long)HDIM * HDIM);
  denom_reduce_kernel<<<HDIM, 256, 0, stream>>>(part, dmaxf);

  // ---- h_t + groupnorm + skip + silu gate
  hgn_kernel<<<B_ROWS, 256, 0, stream>>>(o_b, q_b, out_c, dmaxf, xskip_b,
                                         xupr_b, gn_g, gn_b, out_h, act_b);

  // ---- down projection + residual (256x128 tiles -> 256 blocks, full chip)
  gemm256n128_kernel<0, true><<<dim3(DMODEL / 128, B_ROWS / 256, 1), 512, 0, stream>>>(
      act_b, HDIM, WdownT, HDIM, bdown, out_final, nullptr, DMODEL, x, DMODEL,
      HDIM, 1.f);
}